// Round 6
// baseline (247.093 us; speedup 1.0000x reference)
//
#include <hip/hip_runtime.h>

// Problem constants
#define SEQ   2048
#define BATCH 2
#define DM    1024
#define NH    16
#define DKD   64
#define MROWS (SEQ*BATCH)   // 4096 rows of the [S,B,D] matrices

#define QSCALE 0.18033688011112042f   // (1/8)*log2(e), folded into Q projection

using bf16x8 = __attribute__((ext_vector_type(8))) __bf16;  // MFMA A/B frag (4 VGPRs)
using bf16x4 = __attribute__((ext_vector_type(4))) __bf16;  // 8B pack
using bf16x2 = __attribute__((ext_vector_type(2))) __bf16;  // 4B pack
using f32x4  = __attribute__((ext_vector_type(4))) float;   // MFMA C/D frag

// async global->LDS, 16B per lane; LDS dest must be wave-uniform base + lane*16
__device__ __forceinline__ void gld_lds16(const __bf16* g, __bf16* l) {
  __builtin_amdgcn_global_load_lds(
      (__attribute__((address_space(1))) void*)(g),
      (__attribute__((address_space(3))) void*)(l), 16, 0, 0);
}

// ------------------------------------------------------- fp32 -> bf16 (merged)
__global__ __launch_bounds__(256) void cvt_all(
    const float* __restrict__ s0, const float* __restrict__ s1,
    const float* __restrict__ s2, const float* __restrict__ s3,
    const float* __restrict__ s4, const float* __restrict__ s5,
    const float* __restrict__ s6,
    __bf16* __restrict__ d0, __bf16* __restrict__ d1, __bf16* __restrict__ d2,
    __bf16* __restrict__ d3, __bf16* __restrict__ d4, __bf16* __restrict__ d5,
    __bf16* __restrict__ d6, int n_big, int n_small) {
  int y = blockIdx.y;
  const float* s; __bf16* d;
  switch (y) {
    case 0: s = s0; d = d0; break;
    case 1: s = s1; d = d1; break;
    case 2: s = s2; d = d2; break;
    case 3: s = s3; d = d3; break;
    case 4: s = s4; d = d4; break;
    case 5: s = s5; d = d5; break;
    default: s = s6; d = d6; break;
  }
  int n = (y < 3) ? n_big : n_small;
  int i = (blockIdx.x * 256 + threadIdx.x) * 8;
  if (i >= n) return;
  const float4* sp = (const float4*)(s + i);
  float4 a = sp[0], b = sp[1];
  bf16x8 v;
  v[0]=(__bf16)a.x; v[1]=(__bf16)a.y; v[2]=(__bf16)a.z; v[3]=(__bf16)a.w;
  v[4]=(__bf16)b.x; v[5]=(__bf16)b.y; v[6]=(__bf16)b.z; v[7]=(__bf16)b.w;
  *(bf16x8*)(d + i) = v;
}

// ------------------------------------------------- shared 128x128 GEMM-BT core
__device__ __forceinline__ void gemm_core(const __bf16* __restrict__ A,
                                          const __bf16* __restrict__ Bt,
                                          __bf16* Ash, __bf16* Bsh,
                                          f32x4 acc[4][4], int m0, int n0) {
  const int K = DM;
  int tid = threadIdx.x;
  int lane = tid & 63, quad = lane >> 4, l16 = lane & 15;
  int w = tid >> 6;
  int wm = (w & 1) * 64, wn = (w >> 1) * 64;
  for (int k0 = 0; k0 < K; k0 += 32) {
    __syncthreads();
#pragma unroll
    for (int it = 0; it < 2; ++it) {
      int c   = tid + it * 256;          // 512 chunks of 16B cover 128x32 bf16
      int row = c >> 2, ko = (c & 3) * 8;
      int base = (tid - lane + it * 256) * 8;  // wave-uniform LDS base (elems)
      gld_lds16(A  + (size_t)(m0 + row) * K + k0 + ko, Ash + base);
      gld_lds16(Bt + (size_t)(n0 + row) * K + k0 + ko, Bsh + base);
    }
    __syncthreads();  // drains vmcnt -> LDS valid
    bf16x8 af[4], bfr[4];
#pragma unroll
    for (int mi = 0; mi < 4; mi++)
      af[mi] = *(const bf16x8*)&Ash[(wm + mi * 16 + l16) * 32 + quad * 8];
#pragma unroll
    for (int ni = 0; ni < 4; ni++)
      bfr[ni] = *(const bf16x8*)&Bsh[(wn + ni * 16 + l16) * 32 + quad * 8];
#pragma unroll
    for (int mi = 0; mi < 4; mi++)
#pragma unroll
      for (int ni = 0; ni < 4; ni++)
        acc[mi][ni] = __builtin_amdgcn_mfma_f32_16x16x32_bf16(
            af[mi], bfr[ni], acc[mi][ni], 0, 0, 0);
  }
}

// ------------------------------------------ QKV projections, permuted bf16 out
// grid (8, 32, 3). Q/K out: [H][B][S][DK]; V out: [H][B][DK][S].
// Q output is pre-scaled by QSCALE (softmax fold) in fp32 -> exact.
__global__ __launch_bounds__(256, 3) void gemm_qkv(
    const __bf16* __restrict__ Xq, const __bf16* __restrict__ Xk,
    const __bf16* __restrict__ Xv, const __bf16* __restrict__ Wqkv,
    const float* __restrict__ bqp, const float* __restrict__ bkp,
    const float* __restrict__ bvp,
    __bf16* __restrict__ Qb, __bf16* __restrict__ Kb, __bf16* __restrict__ Vt) {
  __shared__ __bf16 Ash[128 * 32], Bsh[128 * 32];
  __shared__ __bf16 Esh[4][16 * 72];     // per-wave epilogue staging
  int z = blockIdx.z;
  const __bf16* A   = (z == 0) ? Xq : (z == 1) ? Xk : Xv;
  const __bf16* Bt  = Wqkv + (size_t)z * (DM * DM);
  const float* bias = (z == 0) ? bqp : (z == 1) ? bkp : bvp;
  int m0 = blockIdx.y * 128, n0 = blockIdx.x * 128;
  f32x4 acc[4][4] = {};
  gemm_core(A, Bt, Ash, Bsh, acc, m0, n0);

  int tid = threadIdx.x, lane = tid & 63, quad = lane >> 4, l16 = lane & 15;
  int w = tid >> 6, wm = (w & 1) * 64, wn = (w >> 1) * 64;
  __bf16* E = Esh[w];
  int n_base = n0 + wn;                  // 64-aligned -> one head per wave tile
  int hh = n_base >> 6;
  float scale = (z == 0) ? QSCALE : 1.0f;
  float bb[4];
#pragma unroll
  for (int ni = 0; ni < 4; ni++) bb[ni] = bias[n_base + ni * 16 + l16] * scale;

  if (z == 2) {
    // Vt[(hh*B+b)*64+dd][sg]: stage 16 dd-rows (one ni) at a time.
#pragma unroll
    for (int ni = 0; ni < 4; ni++) {
#pragma unroll
      for (int mi = 0; mi < 4; mi++) {
        int s0 = mi * 8 + quad * 2;      // local s (even)
        bf16x2 p0, p1;
        p0[0] = (__bf16)(acc[mi][ni][0] + bb[ni]);
        p0[1] = (__bf16)(acc[mi][ni][2] + bb[ni]);
        p1[0] = (__bf16)(acc[mi][ni][1] + bb[ni]);
        p1[1] = (__bf16)(acc[mi][ni][3] + bb[ni]);
        *(bf16x2*)&E[l16 * 72 + s0]      = p0;   // b = 0
        *(bf16x2*)&E[l16 * 72 + 32 + s0] = p1;   // b = 1
      }
      asm volatile("s_waitcnt lgkmcnt(0)" ::: "memory");
#pragma unroll
      for (int pass = 0; pass < 2; pass++) {
        int ddl = pass * 8 + (lane >> 3);
        int col = (lane & 7) * 8;
        bf16x8 v = *(const bf16x8*)&E[ddl * 72 + col];
        int b2 = col >> 5, sl = col & 31;
        int dd = ni * 16 + ddl;
        int sg = ((m0 + wm) >> 1) + sl;
        *(bf16x8*)&Vt[(((size_t)hh * BATCH + b2) * DKD + dd) * SEQ + sg] = v;
      }
      asm volatile("s_waitcnt lgkmcnt(0)" ::: "memory");
    }
  } else {
    __bf16* Out = (z == 0) ? Qb : Kb;
#pragma unroll
    for (int mi = 0; mi < 4; mi++) {
#pragma unroll
      for (int ni = 0; ni < 4; ni++)
#pragma unroll
        for (int r = 0; r < 4; r++)
          E[(quad * 4 + r) * 72 + ni * 16 + l16] =
              (__bf16)fmaf(acc[mi][ni][r], scale, bb[ni]);
      asm volatile("s_waitcnt lgkmcnt(0)" ::: "memory");
#pragma unroll
      for (int pass = 0; pass < 2; pass++) {
        int row16 = pass * 8 + (lane >> 3);
        int coll  = (lane & 7) * 8;
        bf16x8 v = *(const bf16x8*)&E[row16 * 72 + coll];
        int m = m0 + wm + mi * 16 + row16;
        int s = m >> 1, b2 = m & 1;
        *(bf16x8*)&Out[(((size_t)hh * BATCH + b2) * SEQ + s) * DKD + coll] = v;
      }
      asm volatile("s_waitcnt lgkmcnt(0)" ::: "memory");
    }
  }
}

// --------------------------------- output projection, 64x128 tiles, fp32 out
__global__ __launch_bounds__(256, 3) void gemm_out(
    const __bf16* __restrict__ A, const __bf16* __restrict__ Bt,
    const float* __restrict__ bias, float* __restrict__ out) {
  __shared__ __bf16 Ash[64 * 32], Bsh[128 * 32];
  const int K = DM;
  int m0 = blockIdx.y * 64, n0 = blockIdx.x * 128;
  int tid = threadIdx.x;
  int lane = tid & 63, quad = lane >> 4, l16 = lane & 15;
  int w = tid >> 6;
  int wm = (w & 1) * 32, wn = (w >> 1) * 64;
  f32x4 acc[2][4] = {};
  for (int k0 = 0; k0 < K; k0 += 32) {
    __syncthreads();
    {
      int c = tid;                        // A: 256 chunks (64 rows x 4)
      int row = c >> 2, ko = (c & 3) * 8;
      gld_lds16(A + (size_t)(m0 + row) * K + k0 + ko,
                Ash + (tid - lane) * 8);
    }
#pragma unroll
    for (int it = 0; it < 2; ++it) {      // B: 512 chunks (128 rows x 4)
      int c = tid + it * 256;
      int row = c >> 2, ko = (c & 3) * 8;
      gld_lds16(Bt + (size_t)(n0 + row) * K + k0 + ko,
                Bsh + (tid - lane + it * 256) * 8);
    }
    __syncthreads();
    bf16x8 af[2], bfr[4];
#pragma unroll
    for (int mi = 0; mi < 2; mi++)
      af[mi] = *(const bf16x8*)&Ash[(wm + mi * 16 + l16) * 32 + quad * 8];
#pragma unroll
    for (int ni = 0; ni < 4; ni++)
      bfr[ni] = *(const bf16x8*)&Bsh[(wn + ni * 16 + l16) * 32 + quad * 8];
#pragma unroll
    for (int mi = 0; mi < 2; mi++)
#pragma unroll
      for (int ni = 0; ni < 4; ni++)
        acc[mi][ni] = __builtin_amdgcn_mfma_f32_16x16x32_bf16(
            af[mi], bfr[ni], acc[mi][ni], 0, 0, 0);
  }
#pragma unroll
  for (int ni = 0; ni < 4; ni++) {
    int n = n0 + wn + ni * 16 + l16;
    float bb = bias[n];
#pragma unroll
    for (int mi = 0; mi < 2; mi++) {
#pragma unroll
      for (int r = 0; r < 4; r++) {
        int m = m0 + wm + mi * 16 + quad * 4 + r;
        out[(size_t)m * DM + n] = acc[mi][ni][r] + bb;
      }
    }
  }
}

// -------------------------------------------------------------- flash attention
// 1-D grid of 1024 blocks; block 128 = 2 waves; wave owns 32 q (2 blocks of 16).
// Block n: hb = n&31 (h = hb>>1, b = hb&1), qi = n>>5, q0 = qi*64.
//   -> XCD = n%8 = hb%8: all 16 q-blocks of one (h,b) share an XCD; 4 hb per
//      XCD = 2 MB K/V, fits the 4 MB per-XCD L2 (K/V fetched from HBM once).
// Single-buffered swizzled K/V staging, 24 KB LDS -> 4 blocks/CU resident;
// cross-block overlap hides the per-tile DMA drain. Q pre-scaled by QSCALE;
// softmax = exp2(sc), no shift/max (scale-invariance); per-lane l partials.
__global__ __launch_bounds__(128, 2) void flash_attn(
    const __bf16* __restrict__ Qg, const __bf16* __restrict__ Kg,
    const __bf16* __restrict__ Vtg, __bf16* __restrict__ Xa) {
  __shared__ __bf16 Ksh[64 * 64];
  __shared__ __bf16 Vsh[64 * 64];
  __shared__ __bf16 Psh[2][32 * 64];
  int tid = threadIdx.x, w = tid >> 6, lane = tid & 63;
  int quad = lane >> 4, l16 = lane & 15, sw = l16 & 7;
  int n = blockIdx.x;
  int hb = n & 31, qi = n >> 5;
  int h = hb >> 1, b = hb & 1, q0 = qi * 64;
  size_t hboff = ((size_t)h * BATCH + b) * SEQ * DKD;
  const __bf16* Qp = Qg + hboff;
  const __bf16* Kp = Kg + hboff;
  const __bf16* Vp = Vtg + hboff;        // [DK][SEQ] within (h,b)
  __bf16* Pw = Psh[w];

  // Q frags (MFMA B operand): lane l16 = q, regs = d
  bf16x8 qf[2][2];
#pragma unroll
  for (int qb = 0; qb < 2; qb++)
#pragma unroll
    for (int kk = 0; kk < 2; kk++)
      qf[qb][kk] = *(const bf16x8*)(
          Qp + (size_t)(q0 + w * 32 + qb * 16 + l16) * DKD + kk * 32 + quad * 8);

  f32x4 o[2][4] = {};
  float l_[2] = {0.f, 0.f};              // per-lane partial (disjoint j/quad)

  for (int t = 0; t < SEQ / 64; ++t) {
    int k0 = t * 64;
    __syncthreads();                     // prev compute done -> safe to overwrite
#pragma unroll
    for (int it = 0; it < 4; ++it) {     // K: 512 chunks over 128 threads
      int c = tid + it * 128;
      int r = c >> 3, pp = c & 7;
      int off = (pp ^ (r & 7)) << 3;
      gld_lds16(Kp + (size_t)(k0 + r) * DKD + off, Ksh + c * 8);
    }
#pragma unroll
    for (int it = 0; it < 4; ++it) {     // V: 512 chunks
      int c = tid + it * 128;
      int r = c >> 3, pp = c & 7;
      int off = (pp ^ (r & 7)) << 3;
      gld_lds16(Vp + (size_t)r * SEQ + k0 + off, Vsh + c * 8);
    }
    __syncthreads();                     // vmcnt drain -> LDS valid

    // S^T[j][q]: frag rows j = ji*16 + quad*4 + r, cols q = l16
    f32x4 sc[2][4];
#pragma unroll
    for (int ji = 0; ji < 4; ji++) {
      int rr = ji * 16 + l16;
      bf16x8 kf0 = *(const bf16x8*)&Ksh[rr * 64 + ((quad ^ sw) << 3)];
      bf16x8 kf1 = *(const bf16x8*)&Ksh[rr * 64 + (((4 + quad) ^ sw) << 3)];
#pragma unroll
      for (int qb = 0; qb < 2; qb++) {
        f32x4 t2 = {0.f, 0.f, 0.f, 0.f};
        t2 = __builtin_amdgcn_mfma_f32_16x16x32_bf16(kf0, qf[qb][0], t2, 0, 0, 0);
        t2 = __builtin_amdgcn_mfma_f32_16x16x32_bf16(kf1, qf[qb][1], t2, 0, 0, 0);
        sc[qb][ji] = t2;
      }
    }

    // softmax numerators: p = exp2(sc); accumulate per-lane l partials
#pragma unroll
    for (int qb = 0; qb < 2; qb++) {
#pragma unroll
      for (int ji = 0; ji < 4; ji++) {
        bf16x4 pk;
#pragma unroll
        for (int r = 0; r < 4; r++) {
          float pv = exp2f(sc[qb][ji][r]);
          l_[qb] += pv;
          pk[r] = (__bf16)pv;
        }
        *(bf16x4*)&Pw[(qb * 16 + l16) * 64 +
                      (((ji * 2 + (quad >> 1)) ^ sw) << 3) + ((quad & 1) << 2)] = pk;
      }
    }

    // O += P * V: A = P rows (swizzled b128), B = Vt rows (swizzled b128)
#pragma unroll
    for (int kk = 0; kk < 2; kk++) {
      bf16x8 pa[2];
#pragma unroll
      for (int qb = 0; qb < 2; qb++)
        pa[qb] = *(const bf16x8*)&Pw[(qb * 16 + l16) * 64 +
                                     (((kk * 4 + quad) ^ sw) << 3)];
#pragma unroll
      for (int ni = 0; ni < 4; ni++) {
        int rr = ni * 16 + l16;
        bf16x8 vb = *(const bf16x8*)&Vsh[rr * 64 + (((kk * 4 + quad) ^ sw) << 3)];
#pragma unroll
        for (int qb = 0; qb < 2; qb++)
          o[qb][ni] = __builtin_amdgcn_mfma_f32_16x16x32_bf16(pa[qb], vb,
                                                              o[qb][ni], 0, 0, 0);
      }
    }
  }

  // final l reduction across quads (disjoint j-subsets), then epilogue
#pragma unroll
  for (int qb = 0; qb < 2; qb++) {
    l_[qb] += __shfl_xor(l_[qb], 16, 64);
    l_[qb] += __shfl_xor(l_[qb], 32, 64);
    l_[qb] = 1.0f / l_[qb];
  }
#pragma unroll
  for (int qb = 0; qb < 2; qb++)
#pragma unroll
    for (int r = 0; r < 4; r++) {
      float li = __shfl(l_[qb], quad * 4 + r, 64);
      int q = q0 + w * 32 + qb * 16 + quad * 4 + r;
#pragma unroll
      for (int ni = 0; ni < 4; ni++) {
        int d = ni * 16 + l16;
        Xa[((size_t)q * BATCH + b) * DM + h * DKD + d] =
            (__bf16)(o[qb][ni][r] * li);
      }
    }
}

// ------------------------------------------------------------------- launcher
extern "C" void kernel_launch(void* const* d_in, const int* in_sizes, int n_in,
                              void* d_out, int out_size, void* d_ws,
                              size_t ws_size, hipStream_t stream) {
  (void)in_sizes; (void)n_in; (void)out_size; (void)ws_size;
  const float* query = (const float*)d_in[0];
  const float* key_  = (const float*)d_in[1];
  const float* value = (const float*)d_in[2];
  const float* Wq = (const float*)d_in[3];
  const float* bq = (const float*)d_in[4];
  const float* Wk = (const float*)d_in[5];
  const float* bk = (const float*)d_in[6];
  const float* Wv = (const float*)d_in[7];
  const float* bv = (const float*)d_in[8];
  const float* Wo = (const float*)d_in[9];
  const float* bo = (const float*)d_in[10];

  const size_t NX = (size_t)MROWS * DM;  // 4M elems
  const size_t NW = (size_t)DM * DM;     // 1M elems
  __bf16* p    = (__bf16*)d_ws;
  __bf16* Xq   = p; p += NX;
  __bf16* Xk   = p; p += NX;
  __bf16* Xv   = p; p += NX;
  __bf16* Wqkv = p; p += 3 * NW;
  __bf16* Wob  = p; p += NW;
  __bf16* Qb   = p; p += NX;   // [H][B][S][DK], pre-scaled by QSCALE
  __bf16* Kb   = p; p += NX;   // [H][B][S][DK]
  __bf16* Vt   = p; p += NX;   // [H][B][DK][S]
  __bf16* Xa   = p; p += NX;   // [S*B][D]

  cvt_all<<<dim3((unsigned)(NX / 2048), 7), 256, 0, stream>>>(
      query, key_, value, Wq, Wk, Wv, Wo,
      Xq, Xk, Xv, Wqkv, Wqkv + NW, Wqkv + 2 * NW, Wob, (int)NX, (int)NW);

  gemm_qkv<<<dim3(DM / 128, MROWS / 128, 3), 256, 0, stream>>>(
      Xq, Xk, Xv, Wqkv, bq, bk, bv, Qb, Kb, Vt);
  flash_attn<<<dim3(1024), 128, 0, stream>>>(Qb, Kb, Vt, Xa);
  gemm_out<<<dim3(DM / 128, MROWS / 64), 256, 0, stream>>>(
      Xa, Wob, bo, (float*)d_out);
}

// Round 7
// 234.525 us; speedup vs baseline: 1.0536x; 1.0536x over previous
//
#include <hip/hip_runtime.h>

// Problem constants
#define SEQ   2048
#define BATCH 2
#define DM    1024
#define NH    16
#define DKD   64
#define MROWS (SEQ*BATCH)   // 4096 rows of the [S,B,D] matrices

#define QSCALE 0.18033688011112042f   // (1/8)*log2(e), folded into Q projection

using bf16x8 = __attribute__((ext_vector_type(8))) __bf16;  // MFMA A/B frag (4 VGPRs)
using bf16x4 = __attribute__((ext_vector_type(4))) __bf16;  // 8B pack
using bf16x2 = __attribute__((ext_vector_type(2))) __bf16;  // 4B pack
using f32x4  = __attribute__((ext_vector_type(4))) float;   // MFMA C/D frag

// async global->LDS, 16B per lane; LDS dest must be wave-uniform base + lane*16
__device__ __forceinline__ void gld_lds16(const __bf16* g, __bf16* l) {
  __builtin_amdgcn_global_load_lds(
      (__attribute__((address_space(1))) void*)(g),
      (__attribute__((address_space(3))) void*)(l), 16, 0, 0);
}

// ------------------------------------------------------- fp32 -> bf16 (merged)
__global__ __launch_bounds__(256) void cvt_all(
    const float* __restrict__ s0, const float* __restrict__ s1,
    const float* __restrict__ s2, const float* __restrict__ s3,
    const float* __restrict__ s4, const float* __restrict__ s5,
    const float* __restrict__ s6,
    __bf16* __restrict__ d0, __bf16* __restrict__ d1, __bf16* __restrict__ d2,
    __bf16* __restrict__ d3, __bf16* __restrict__ d4, __bf16* __restrict__ d5,
    __bf16* __restrict__ d6, int n_big, int n_small) {
  int y = blockIdx.y;
  const float* s; __bf16* d;
  switch (y) {
    case 0: s = s0; d = d0; break;
    case 1: s = s1; d = d1; break;
    case 2: s = s2; d = d2; break;
    case 3: s = s3; d = d3; break;
    case 4: s = s4; d = d4; break;
    case 5: s = s5; d = d5; break;
    default: s = s6; d = d6; break;
  }
  int n = (y < 3) ? n_big : n_small;
  int i = (blockIdx.x * 256 + threadIdx.x) * 8;
  if (i >= n) return;
  const float4* sp = (const float4*)(s + i);
  float4 a = sp[0], b = sp[1];
  bf16x8 v;
  v[0]=(__bf16)a.x; v[1]=(__bf16)a.y; v[2]=(__bf16)a.z; v[3]=(__bf16)a.w;
  v[4]=(__bf16)b.x; v[5]=(__bf16)b.y; v[6]=(__bf16)b.z; v[7]=(__bf16)b.w;
  *(bf16x8*)(d + i) = v;
}

// ------------------------------------------------- shared 128x128 GEMM-BT core
__device__ __forceinline__ void gemm_core(const __bf16* __restrict__ A,
                                          const __bf16* __restrict__ Bt,
                                          __bf16* Ash, __bf16* Bsh,
                                          f32x4 acc[4][4], int m0, int n0) {
  const int K = DM;
  int tid = threadIdx.x;
  int lane = tid & 63, quad = lane >> 4, l16 = lane & 15;
  int w = tid >> 6;
  int wm = (w & 1) * 64, wn = (w >> 1) * 64;
  for (int k0 = 0; k0 < K; k0 += 32) {
    __syncthreads();
#pragma unroll
    for (int it = 0; it < 2; ++it) {
      int c   = tid + it * 256;          // 512 chunks of 16B cover 128x32 bf16
      int row = c >> 2, ko = (c & 3) * 8;
      int base = (tid - lane + it * 256) * 8;  // wave-uniform LDS base (elems)
      gld_lds16(A  + (size_t)(m0 + row) * K + k0 + ko, Ash + base);
      gld_lds16(Bt + (size_t)(n0 + row) * K + k0 + ko, Bsh + base);
    }
    __syncthreads();  // drains vmcnt -> LDS valid
    bf16x8 af[4], bfr[4];
#pragma unroll
    for (int mi = 0; mi < 4; mi++)
      af[mi] = *(const bf16x8*)&Ash[(wm + mi * 16 + l16) * 32 + quad * 8];
#pragma unroll
    for (int ni = 0; ni < 4; ni++)
      bfr[ni] = *(const bf16x8*)&Bsh[(wn + ni * 16 + l16) * 32 + quad * 8];
#pragma unroll
    for (int mi = 0; mi < 4; mi++)
#pragma unroll
      for (int ni = 0; ni < 4; ni++)
        acc[mi][ni] = __builtin_amdgcn_mfma_f32_16x16x32_bf16(
            af[mi], bfr[ni], acc[mi][ni], 0, 0, 0);
  }
}

// ------------------------------------------ QKV projections, permuted bf16 out
// grid (8, 32, 3). Q/K out: [H][B][S][DK]; V out: [H][B][DK][S].
// Q output is pre-scaled by QSCALE (softmax fold) in fp32 -> exact.
__global__ __launch_bounds__(256, 3) void gemm_qkv(
    const __bf16* __restrict__ Xq, const __bf16* __restrict__ Xk,
    const __bf16* __restrict__ Xv, const __bf16* __restrict__ Wqkv,
    const float* __restrict__ bqp, const float* __restrict__ bkp,
    const float* __restrict__ bvp,
    __bf16* __restrict__ Qb, __bf16* __restrict__ Kb, __bf16* __restrict__ Vt) {
  __shared__ __bf16 Ash[128 * 32], Bsh[128 * 32];
  __shared__ __bf16 Esh[4][16 * 72];     // per-wave epilogue staging
  int z = blockIdx.z;
  const __bf16* A   = (z == 0) ? Xq : (z == 1) ? Xk : Xv;
  const __bf16* Bt  = Wqkv + (size_t)z * (DM * DM);
  const float* bias = (z == 0) ? bqp : (z == 1) ? bkp : bvp;
  int m0 = blockIdx.y * 128, n0 = blockIdx.x * 128;
  f32x4 acc[4][4] = {};
  gemm_core(A, Bt, Ash, Bsh, acc, m0, n0);

  int tid = threadIdx.x, lane = tid & 63, quad = lane >> 4, l16 = lane & 15;
  int w = tid >> 6, wm = (w & 1) * 64, wn = (w >> 1) * 64;
  __bf16* E = Esh[w];
  int n_base = n0 + wn;                  // 64-aligned -> one head per wave tile
  int hh = n_base >> 6;
  float scale = (z == 0) ? QSCALE : 1.0f;
  float bb[4];
#pragma unroll
  for (int ni = 0; ni < 4; ni++) bb[ni] = bias[n_base + ni * 16 + l16] * scale;

  if (z == 2) {
    // Vt[(hh*B+b)*64+dd][sg]: stage 16 dd-rows (one ni) at a time.
#pragma unroll
    for (int ni = 0; ni < 4; ni++) {
#pragma unroll
      for (int mi = 0; mi < 4; mi++) {
        int s0 = mi * 8 + quad * 2;      // local s (even)
        bf16x2 p0, p1;
        p0[0] = (__bf16)(acc[mi][ni][0] + bb[ni]);
        p0[1] = (__bf16)(acc[mi][ni][2] + bb[ni]);
        p1[0] = (__bf16)(acc[mi][ni][1] + bb[ni]);
        p1[1] = (__bf16)(acc[mi][ni][3] + bb[ni]);
        *(bf16x2*)&E[l16 * 72 + s0]      = p0;   // b = 0
        *(bf16x2*)&E[l16 * 72 + 32 + s0] = p1;   // b = 1
      }
      asm volatile("s_waitcnt lgkmcnt(0)" ::: "memory");
#pragma unroll
      for (int pass = 0; pass < 2; pass++) {
        int ddl = pass * 8 + (lane >> 3);
        int col = (lane & 7) * 8;
        bf16x8 v = *(const bf16x8*)&E[ddl * 72 + col];
        int b2 = col >> 5, sl = col & 31;
        int dd = ni * 16 + ddl;
        int sg = ((m0 + wm) >> 1) + sl;
        *(bf16x8*)&Vt[(((size_t)hh * BATCH + b2) * DKD + dd) * SEQ + sg] = v;
      }
      asm volatile("s_waitcnt lgkmcnt(0)" ::: "memory");
    }
  } else {
    __bf16* Out = (z == 0) ? Qb : Kb;
#pragma unroll
    for (int mi = 0; mi < 4; mi++) {
#pragma unroll
      for (int ni = 0; ni < 4; ni++)
#pragma unroll
        for (int r = 0; r < 4; r++)
          E[(quad * 4 + r) * 72 + ni * 16 + l16] =
              (__bf16)fmaf(acc[mi][ni][r], scale, bb[ni]);
      asm volatile("s_waitcnt lgkmcnt(0)" ::: "memory");
#pragma unroll
      for (int pass = 0; pass < 2; pass++) {
        int row16 = pass * 8 + (lane >> 3);
        int coll  = (lane & 7) * 8;
        bf16x8 v = *(const bf16x8*)&E[row16 * 72 + coll];
        int m = m0 + wm + mi * 16 + row16;
        int s = m >> 1, b2 = m & 1;
        *(bf16x8*)&Out[(((size_t)hh * BATCH + b2) * SEQ + s) * DKD + coll] = v;
      }
      asm volatile("s_waitcnt lgkmcnt(0)" ::: "memory");
    }
  }
}

// --------------------------------- output projection, 64x128 tiles, fp32 out
__global__ __launch_bounds__(256, 3) void gemm_out(
    const __bf16* __restrict__ A, const __bf16* __restrict__ Bt,
    const float* __restrict__ bias, float* __restrict__ out) {
  __shared__ __bf16 Ash[64 * 32], Bsh[128 * 32];
  const int K = DM;
  int m0 = blockIdx.y * 64, n0 = blockIdx.x * 128;
  int tid = threadIdx.x;
  int lane = tid & 63, quad = lane >> 4, l16 = lane & 15;
  int w = tid >> 6;
  int wm = (w & 1) * 32, wn = (w >> 1) * 64;
  f32x4 acc[2][4] = {};
  for (int k0 = 0; k0 < K; k0 += 32) {
    __syncthreads();
    {
      int c = tid;                        // A: 256 chunks (64 rows x 4)
      int row = c >> 2, ko = (c & 3) * 8;
      gld_lds16(A + (size_t)(m0 + row) * K + k0 + ko,
                Ash + (tid - lane) * 8);
    }
#pragma unroll
    for (int it = 0; it < 2; ++it) {      // B: 512 chunks (128 rows x 4)
      int c = tid + it * 256;
      int row = c >> 2, ko = (c & 3) * 8;
      gld_lds16(Bt + (size_t)(n0 + row) * K + k0 + ko,
                Bsh + (tid - lane + it * 256) * 8);
    }
    __syncthreads();
    bf16x8 af[2], bfr[4];
#pragma unroll
    for (int mi = 0; mi < 2; mi++)
      af[mi] = *(const bf16x8*)&Ash[(wm + mi * 16 + l16) * 32 + quad * 8];
#pragma unroll
    for (int ni = 0; ni < 4; ni++)
      bfr[ni] = *(const bf16x8*)&Bsh[(wn + ni * 16 + l16) * 32 + quad * 8];
#pragma unroll
    for (int mi = 0; mi < 2; mi++)
#pragma unroll
      for (int ni = 0; ni < 4; ni++)
        acc[mi][ni] = __builtin_amdgcn_mfma_f32_16x16x32_bf16(
            af[mi], bfr[ni], acc[mi][ni], 0, 0, 0);
  }
#pragma unroll
  for (int ni = 0; ni < 4; ni++) {
    int n = n0 + wn + ni * 16 + l16;
    float bb = bias[n];
#pragma unroll
    for (int mi = 0; mi < 2; mi++) {
#pragma unroll
      for (int r = 0; r < 4; r++) {
        int m = m0 + wm + mi * 16 + quad * 4 + r;
        out[(size_t)m * DM + n] = acc[mi][ni][r] + bb;
      }
    }
  }
}

// -------------------------------------------------------------- flash attention
// 1-D grid of 512 blocks; block 256 = 4 waves; wave owns 32 q (2 blocks of 16).
// Block n: hb = n&31 (h=hb>>1, b=hb&1), qi = n>>5, q0 = qi*128.
//   XCD = n%8 = hb%8: all 16 q-blocks of one (h,b) share an XCD; 4 hb x 0.5 MB
//   K/V per XCD = 2 MB resident in the 4 MB L2 -> K/V from HBM once, DMA
//   drains hit L2 (~200 cyc) instead of HBM (~900).
// Double-buffered swizzled K/V staging: one barrier per tile; DMA(t+1) issued
// after the barrier, drained at the next barrier (a full compute phase later).
// Q pre-scaled by QSCALE; softmax = exp2(sc), no shift/max (scale-invariance);
// per-lane l partials (quads own disjoint j), reduced once after the K-loop.
__global__ __launch_bounds__(256, 2) void flash_attn(
    const __bf16* __restrict__ Qg, const __bf16* __restrict__ Kg,
    const __bf16* __restrict__ Vtg, __bf16* __restrict__ Xa) {
  __shared__ __bf16 Ksh[2][64 * 64];
  __shared__ __bf16 Vsh[2][64 * 64];
  __shared__ __bf16 Psh[4][32 * 64];
  int tid = threadIdx.x, w = tid >> 6, lane = tid & 63;
  int quad = lane >> 4, l16 = lane & 15, sw = l16 & 7;
  int n = blockIdx.x;
  int hb = n & 31, qi = n >> 5;
  int h = hb >> 1, b = hb & 1, q0 = qi * 128;
  size_t hboff = ((size_t)h * BATCH + b) * SEQ * DKD;
  const __bf16* Qp = Qg + hboff;
  const __bf16* Kp = Kg + hboff;
  const __bf16* Vp = Vtg + hboff;        // [DK][SEQ] within (h,b)
  __bf16* Pw = Psh[w];

  // Q frags (MFMA B operand): lane l16 = q, regs = d
  bf16x8 qf[2][2];
#pragma unroll
  for (int qb = 0; qb < 2; qb++)
#pragma unroll
    for (int kk = 0; kk < 2; kk++)
      qf[qb][kk] = *(const bf16x8*)(
          Qp + (size_t)(q0 + w * 32 + qb * 16 + l16) * DKD + kk * 32 + quad * 8);

  f32x4 o[2][4] = {};
  float l_[2] = {0.f, 0.f};              // per-lane partial (disjoint j/quad)

  // stage tile 0 into buf 0 (512 chunks K + 512 V over 256 threads)
#pragma unroll
  for (int it = 0; it < 2; ++it) {
    int c = tid + it * 256;
    int r = c >> 3, pp = c & 7;
    int off = (pp ^ (r & 7)) << 3;
    gld_lds16(Kp + (size_t)r * DKD + off, Ksh[0] + c * 8);
    gld_lds16(Vp + (size_t)r * SEQ + off, Vsh[0] + c * 8);
  }

  for (int t = 0; t < SEQ / 64; ++t) {
    __syncthreads();                       // drains DMA for buf[t&1]
    if (t + 1 < SEQ / 64) {
      int k0n = (t + 1) * 64, bn = (t + 1) & 1;
#pragma unroll
      for (int it = 0; it < 2; ++it) {
        int c = tid + it * 256;
        int r = c >> 3, pp = c & 7;
        int off = (pp ^ (r & 7)) << 3;
        gld_lds16(Kp + (size_t)(k0n + r) * DKD + off, Ksh[bn] + c * 8);
        gld_lds16(Vp + (size_t)r * SEQ + k0n + off, Vsh[bn] + c * 8);
      }
    }
    const __bf16* Kb_ = Ksh[t & 1];
    const __bf16* Vb_ = Vsh[t & 1];

    // S^T[j][q]: frag rows j = ji*16 + quad*4 + r, cols q = l16
    f32x4 sc[2][4];
#pragma unroll
    for (int ji = 0; ji < 4; ji++) {
      int rr = ji * 16 + l16;
      bf16x8 kf0 = *(const bf16x8*)&Kb_[rr * 64 + ((quad ^ sw) << 3)];
      bf16x8 kf1 = *(const bf16x8*)&Kb_[rr * 64 + (((4 + quad) ^ sw) << 3)];
#pragma unroll
      for (int qb = 0; qb < 2; qb++) {
        f32x4 t2 = {0.f, 0.f, 0.f, 0.f};
        t2 = __builtin_amdgcn_mfma_f32_16x16x32_bf16(kf0, qf[qb][0], t2, 0, 0, 0);
        t2 = __builtin_amdgcn_mfma_f32_16x16x32_bf16(kf1, qf[qb][1], t2, 0, 0, 0);
        sc[qb][ji] = t2;
      }
    }

    // softmax numerators: p = exp2(sc); accumulate per-lane l partials
#pragma unroll
    for (int qb = 0; qb < 2; qb++) {
#pragma unroll
      for (int ji = 0; ji < 4; ji++) {
        bf16x4 pk;
#pragma unroll
        for (int r = 0; r < 4; r++) {
          float pv = exp2f(sc[qb][ji][r]);
          l_[qb] += pv;
          pk[r] = (__bf16)pv;
        }
        *(bf16x4*)&Pw[(qb * 16 + l16) * 64 +
                      (((ji * 2 + (quad >> 1)) ^ sw) << 3) + ((quad & 1) << 2)] = pk;
      }
    }

    // O += P * V: A = P rows (swizzled b128), B = Vt rows (swizzled b128)
#pragma unroll
    for (int kk = 0; kk < 2; kk++) {
      bf16x8 pa[2];
#pragma unroll
      for (int qb = 0; qb < 2; qb++)
        pa[qb] = *(const bf16x8*)&Pw[(qb * 16 + l16) * 64 +
                                     (((kk * 4 + quad) ^ sw) << 3)];
#pragma unroll
      for (int ni = 0; ni < 4; ni++) {
        int rr = ni * 16 + l16;
        bf16x8 vb = *(const bf16x8*)&Vb_[rr * 64 + (((kk * 4 + quad) ^ sw) << 3)];
#pragma unroll
        for (int qb = 0; qb < 2; qb++)
          o[qb][ni] = __builtin_amdgcn_mfma_f32_16x16x32_bf16(pa[qb], vb,
                                                              o[qb][ni], 0, 0, 0);
      }
    }
  }

  // final l reduction across quads (disjoint j-subsets), then epilogue
#pragma unroll
  for (int qb = 0; qb < 2; qb++) {
    l_[qb] += __shfl_xor(l_[qb], 16, 64);
    l_[qb] += __shfl_xor(l_[qb], 32, 64);
    l_[qb] = 1.0f / l_[qb];
  }
#pragma unroll
  for (int qb = 0; qb < 2; qb++)
#pragma unroll
    for (int r = 0; r < 4; r++) {
      float li = __shfl(l_[qb], quad * 4 + r, 64);
      int q = q0 + w * 32 + qb * 16 + quad * 4 + r;
#pragma unroll
      for (int ni = 0; ni < 4; ni++) {
        int d = ni * 16 + l16;
        Xa[((size_t)q * BATCH + b) * DM + h * DKD + d] =
            (__bf16)(o[qb][ni][r] * li);
      }
    }
}

// ------------------------------------------------------------------- launcher
extern "C" void kernel_launch(void* const* d_in, const int* in_sizes, int n_in,
                              void* d_out, int out_size, void* d_ws,
                              size_t ws_size, hipStream_t stream) {
  (void)in_sizes; (void)n_in; (void)out_size; (void)ws_size;
  const float* query = (const float*)d_in[0];
  const float* key_  = (const float*)d_in[1];
  const float* value = (const float*)d_in[2];
  const float* Wq = (const float*)d_in[3];
  const float* bq = (const float*)d_in[4];
  const float* Wk = (const float*)d_in[5];
  const float* bk = (const float*)d_in[6];
  const float* Wv = (const float*)d_in[7];
  const float* bv = (const float*)d_in[8];
  const float* Wo = (const float*)d_in[9];
  const float* bo = (const float*)d_in[10];

  const size_t NX = (size_t)MROWS * DM;  // 4M elems
  const size_t NW = (size_t)DM * DM;     // 1M elems
  __bf16* p    = (__bf16*)d_ws;
  __bf16* Xq   = p; p += NX;             // also reused as Xa after gemm_qkv
  __bf16* Xk   = p; p += NX;
  __bf16* Xv   = p; p += NX;
  __bf16* Wqkv = p; p += 3 * NW;
  __bf16* Wob  = p; p += NW;
  __bf16* Qb   = p; p += NX;   // [H][B][S][DK], pre-scaled by QSCALE
  __bf16* Kb   = p; p += NX;   // [H][B][S][DK]
  __bf16* Vt   = p; p += NX;   // [H][B][DK][S]
  __bf16* Xa   = Xq;           // [S*B][D] (aliases Xq, dead after gemm_qkv)

  cvt_all<<<dim3((unsigned)(NX / 2048), 7), 256, 0, stream>>>(
      query, key_, value, Wq, Wk, Wv, Wo,
      Xq, Xk, Xv, Wqkv, Wqkv + NW, Wqkv + 2 * NW, Wob, (int)NX, (int)NW);

  gemm_qkv<<<dim3(DM / 128, MROWS / 128, 3), 256, 0, stream>>>(
      Xq, Xk, Xv, Wqkv, bq, bk, bv, Qb, Kb, Vt);
  flash_attn<<<dim3(512), 256, 0, stream>>>(Qb, Kb, Vt, Xa);
  gemm_out<<<dim3(DM / 128, MROWS / 64), 256, 0, stream>>>(
      Xa, Wob, bo, (float*)d_out);
}